// Round 12
// baseline (585.272 us; speedup 1.0000x reference)
//
#include <hip/hip_runtime.h>
#include <cstddef>

#define T_ 64
#define B_ 256
#define D_ 512
#define L_ 50
#define A_ 18
#define H_ 32

typedef __attribute__((ext_vector_type(8))) short short8;
typedef __attribute__((ext_vector_type(4))) float f32x4;

// ---- workspace float offsets ----
constexpr size_t WS_LC = 0;              // [16384*50]
constexpr size_t WS_CC = 819200;         // [16384*32]
constexpr size_t WS_DP = 1868416;        // [16384][1792] dp^T rows: [h][52pad]

__device__ __forceinline__ float sigf(float x) { return 1.f / (1.f + expf(-x)); }

__device__ __forceinline__ short f2bf_rne(float f) {
  unsigned u = __float_as_uint(f);
  return (short)((u + 0x7fffu + ((u >> 16) & 1u)) >> 16);
}
__device__ __forceinline__ float bcast(float v, int l) {
  return __int_as_float(__builtin_amdgcn_readlane(__float_as_int(v), l));
}
__device__ __forceinline__ void glds16(const float* g, float* l) {
  __builtin_amdgcn_global_load_lds((const __attribute__((address_space(1))) unsigned*)g,
                                   (__attribute__((address_space(3))) unsigned*)l, 16, 0, 0);
}
__device__ __forceinline__ void glds4(const float* g, float* l) {
  __builtin_amdgcn_global_load_lds((const __attribute__((address_space(1))) unsigned*)g,
                                   (__attribute__((address_space(3))) unsigned*)l, 4, 0, 0);
}

// ---------------------------------------------------------------------------
// precompute4 (unchanged from rounds 9-11)
// ---------------------------------------------------------------------------
__global__ __launch_bounds__(256) void precompute4(
    const float* __restrict__ state,
    const float* __restrict__ W_attn, const float* __restrict__ b_attn,
    const float* __restrict__ W_comb, const float* __restrict__ b_comb,
    float* __restrict__ lc, float* __restrict__ cc) {
  extern __shared__ char pm3[];
  float* As = (float*)pm3;                 // [4 slots][4 waves][512] = 32 KB
  short* Bf = (short*)(pm3 + 32768);       // [2 hi/lo][4 kc][6 nt][64][8] = 48 KB
  const int tid = threadIdx.x;
  const int wave = tid >> 6, lane = tid & 63;
  const int r0 = blockIdx.x * 64;

  const int srow = lane >> 3;
  const int scol = (((lane & 7) * 16) ^ (srow << 4)) >> 2;
  const int crow = lane & 15, g = lane >> 4;
  const int cb0 = (g * 32) ^ ((crow & 7) << 4);

  f32x4 acc[6];
#pragma unroll
  for (int nt = 0; nt < 6; ++nt) acc[nt] = {0.f, 0.f, 0.f, 0.f};

#define STAGE_A(KI, SLOT)                                                       \
  {                                                                             \
    float* dst_ = As + ((SLOT) * 4 + wave) * 512;                               \
    _Pragma("unroll")                                                           \
    for (int i_ = 0; i_ < 2; ++i_) {                                            \
      const float* src_ = state +                                               \
          (size_t)(r0 + wave * 16 + i_ * 8 + srow) * 512 + (KI) * 32 + scol;    \
      glds16(src_, dst_ + i_ * 256);                                            \
    }                                                                           \
  }

  auto stageB = [&](int ko) {
#pragma unroll
    for (int it = 0; it < 6; ++it) {
      int u = tid + it * 256;
      int l = u & 63;
      int nt = (u >> 6) % 6;
      int c = u / 384;
      int n = nt * 16 + (l & 15);
      int kb = ko * 128 + c * 32 + ((l >> 4) << 3);
      f32x4 v0 = {0.f, 0.f, 0.f, 0.f}, v1 = {0.f, 0.f, 0.f, 0.f};
      if (n < 50) {
        const f32x4* s = (const f32x4*)(W_attn + (size_t)n * 544 + kb);
        v0 = s[0]; v1 = s[1];
      } else if (n < 82) {
        const f32x4* s = (const f32x4*)(W_comb + (size_t)(n - 50) * 1024 + 512 + kb);
        v0 = s[0]; v1 = s[1];
      }
      short8 hi, lo;
#pragma unroll
      for (int j = 0; j < 4; ++j) {
        unsigned ua = __float_as_uint(v0[j]), ha = ua & 0xffff0000u;
        hi[j] = (short)(ha >> 16);
        lo[j] = f2bf_rne(v0[j] - __uint_as_float(ha));
        unsigned ub = __float_as_uint(v1[j]), hb = ub & 0xffff0000u;
        hi[4 + j] = (short)(hb >> 16);
        lo[4 + j] = f2bf_rne(v1[j] - __uint_as_float(hb));
      }
      *(short8*)&Bf[(((0 * 4 + c) * 6 + nt) * 64 + l) * 8] = hi;
      *(short8*)&Bf[(((1 * 4 + c) * 6 + nt) * 64 + l) * 8] = lo;
    }
  };

  STAGE_A(0, 0);
  STAGE_A(1, 1);
  STAGE_A(2, 2);
  stageB(0);
  asm volatile("s_waitcnt lgkmcnt(0)" ::: "memory");
  __builtin_amdgcn_s_barrier();

  for (int ko = 0; ko < 4; ++ko) {
    if (ko > 0) {
      __builtin_amdgcn_s_barrier();
      stageB(ko);
      asm volatile("s_waitcnt lgkmcnt(0)" ::: "memory");
      __builtin_amdgcn_s_barrier();
    }
#pragma unroll
    for (int c = 0; c < 4; ++c) {
      const int ki = ko * 4 + c;
      if (ki < 13) {
        STAGE_A(ki + 3, (ki + 3) & 3);
        asm volatile("s_waitcnt vmcnt(6)" ::: "memory");
      } else if (ki == 13) {
        asm volatile("s_waitcnt vmcnt(4)" ::: "memory");
      } else if (ki == 14) {
        asm volatile("s_waitcnt vmcnt(2)" ::: "memory");
      } else {
        asm volatile("s_waitcnt vmcnt(0)" ::: "memory");
      }
      __builtin_amdgcn_sched_barrier(0);
      const char* ab = (const char*)(As + ((ki & 3) * 4 + wave) * 512) + crow * 128;
      f32x4 a0 = *(const f32x4*)(ab + cb0);
      f32x4 a1 = *(const f32x4*)(ab + (cb0 ^ 16));
      short8 ahi, alo;
#pragma unroll
      for (int j = 0; j < 4; ++j) {
        unsigned ua = __float_as_uint(a0[j]), ha = ua & 0xffff0000u;
        ahi[j] = (short)(ha >> 16);
        alo[j] = f2bf_rne(a0[j] - __uint_as_float(ha));
        unsigned ub = __float_as_uint(a1[j]), hb = ub & 0xffff0000u;
        ahi[4 + j] = (short)(hb >> 16);
        alo[4 + j] = f2bf_rne(a1[j] - __uint_as_float(hb));
      }
#pragma unroll
      for (int nt = 0; nt < 6; ++nt) {
        short8 bh = *(const short8*)&Bf[(((0 * 4 + c) * 6 + nt) * 64 + lane) * 8];
        short8 bl = *(const short8*)&Bf[(((1 * 4 + c) * 6 + nt) * 64 + lane) * 8];
        acc[nt] = __builtin_amdgcn_mfma_f32_16x16x32_bf16(ahi, bh, acc[nt], 0, 0, 0);
        acc[nt] = __builtin_amdgcn_mfma_f32_16x16x32_bf16(alo, bh, acc[nt], 0, 0, 0);
        acc[nt] = __builtin_amdgcn_mfma_f32_16x16x32_bf16(ahi, bl, acc[nt], 0, 0, 0);
      }
    }
  }
#undef STAGE_A

#pragma unroll
  for (int nt = 0; nt < 6; ++nt) {
    const int n = nt * 16 + crow;
    float bias = 0.f;
    if (n < 50) bias = b_attn[n];
    else if (n < 82) bias = b_comb[n - 50];
#pragma unroll
    for (int reg = 0; reg < 4; ++reg) {
      const int r = r0 + wave * 16 + (g << 2) + reg;
      const float vv = acc[nt][reg] + bias;
      if (n < 50) lc[(size_t)r * 50 + n] = vv;
      else if (n < 82) cc[(size_t)r * 32 + (n - 50)] = vv;
    }
  }
}

// ---------------------------------------------------------------------------
// dp_gemm5: r5's proven 3-slot loop (vmcnt(8)/store-aware vmcnt(16)) with
// OPERAND-SWAPPED MFMA: acc = mfma(W_frag, demo_frag) computes dp^T[h][m]
// directly in registers (same products, same k-order -> bitwise-identical dp).
// Stores: per-tile magic-div, 8 stores of 4x64B contiguous sectors each.
// LDS 160 KB: 96 KB A-ring + 64 KB B-frags.
// ---------------------------------------------------------------------------
__global__ __launch_bounds__(512, 2) void dp_gemm5(const float* __restrict__ demo,
                                                   const float* __restrict__ W_comb,
                                                   float* __restrict__ dp) {
  extern __shared__ char smraw[];
  float* Abuf = (float*)smraw;                    // [3][8192] floats = 96 KB
  short* frag = (short*)(smraw + 98304);          // [2][16][2][64][8] = 64 KB
  const int tid = threadIdx.x;

  for (int f = tid; f < 16384; f += 512) {
    int j = f & 7, l = (f >> 3) & 63, nt = (f >> 9) & 1, c = f >> 10;
    int n = nt * 16 + (l & 15);
    int k = c * 32 + ((l >> 4) << 3) + j;
    float v = W_comb[(size_t)n * 1024 + k];
    unsigned u = __float_as_uint(v);
    unsigned hb = u & 0xffff0000u;
    frag[(((0 * 16 + c) * 2 + nt) * 64 + l) * 8 + j] = (short)(hb >> 16);
    frag[(((1 * 16 + c) * 2 + nt) * 64 + l) * 8 + j] = f2bf_rne(v - __uint_as_float(hb));
  }
  __syncthreads();

  const int wave = tid >> 6, lane = tid & 63;
  const size_t row0 = (size_t)blockIdx.x * 3200;  // 25 tiles x 128 rows

  int rrl[4], gcol[4];
#pragma unroll
  for (int i = 0; i < 4; ++i) {
    rrl[i] = wave * 16 + i * 4 + (lane >> 4);
    gcol[i] = ((((lane & 15) * 16) ^ ((rrl[i] & 7) << 4)) >> 2);
  }
  const int rr = wave * 16 + (lane & 15);
  const int g = lane >> 4;
  const int h0 = (lane >> 4) * 4;                 // D-row base after operand swap

  f32x4 acc0 = {0.f, 0.f, 0.f, 0.f}, acc1 = {0.f, 0.f, 0.f, 0.f};

#define STAGE(Q, SLOT)                                                          \
  {                                                                             \
    const int tile_ = (Q) >> 3, kc_ = (Q) & 7;                                  \
    const size_t rbase_ = row0 + (size_t)tile_ * 128;                           \
    float* dst_ = Abuf + (SLOT) * 8192 + wave * 1024;                           \
    _Pragma("unroll")                                                           \
    for (int i = 0; i < 4; ++i) {                                               \
      const float* src_ = demo + (rbase_ + rrl[i]) * 512 + kc_ * 64 + gcol[i];  \
      glds16(src_, dst_ + i * 256);                                             \
    }                                                                           \
  }

  STAGE(0, 0);
  STAGE(1, 1);
  for (int q = 0; q < 200; ++q) {
    const int q2 = (q + 2 < 200) ? q + 2 : 199;   // clamped restage, uniform count
    STAGE(q2, (q + 2) % 3);
    if (q >= 8 && (q & 7) <= 1) {
      asm volatile("s_waitcnt vmcnt(16)" ::: "memory");   // stores may stay in flight
    } else {
      asm volatile("s_waitcnt vmcnt(8)" ::: "memory");
    }
    __builtin_amdgcn_sched_barrier(0);
    if ((q & 7) == 0) {
      acc0 = {0.f, 0.f, 0.f, 0.f};
      acc1 = {0.f, 0.f, 0.f, 0.f};
    }
    const char* ab = (const char*)(Abuf + (q % 3) * 8192) + rr * 256;
#pragma unroll
    for (int sub = 0; sub < 2; ++sub) {
      const int b0 = (sub * 128 + g * 32) ^ ((rr & 7) << 4);
      f32x4 a0 = *(const f32x4*)(ab + b0);
      f32x4 a1 = *(const f32x4*)(ab + (b0 ^ 16));
      short8 ahi, alo;
#pragma unroll
      for (int j = 0; j < 4; ++j) {
        float v = a0[j];
        unsigned u = __float_as_uint(v), hb = u & 0xffff0000u;
        ahi[j] = (short)(hb >> 16);
        alo[j] = f2bf_rne(v - __uint_as_float(hb));
        float w = a1[j];
        unsigned u2 = __float_as_uint(w), hb2 = u2 & 0xffff0000u;
        ahi[4 + j] = (short)(hb2 >> 16);
        alo[4 + j] = f2bf_rne(w - __uint_as_float(hb2));
      }
      const int ck = (q & 7) * 2 + sub;
      short8 bh0 = *(const short8*)&frag[(((0 + ck) * 2 + 0) * 64 + lane) * 8];
      short8 bh1 = *(const short8*)&frag[(((0 + ck) * 2 + 1) * 64 + lane) * 8];
      short8 bl0 = *(const short8*)&frag[(((16 + ck) * 2 + 0) * 64 + lane) * 8];
      short8 bl1 = *(const short8*)&frag[(((16 + ck) * 2 + 1) * 64 + lane) * 8];
      // operand-swapped: D = W_chunk . demo_chunk^T = dp^T tile
      acc0 = __builtin_amdgcn_mfma_f32_16x16x32_bf16(bh0, ahi, acc0, 0, 0, 0);
      acc1 = __builtin_amdgcn_mfma_f32_16x16x32_bf16(bh1, ahi, acc1, 0, 0, 0);
      acc0 = __builtin_amdgcn_mfma_f32_16x16x32_bf16(bh0, alo, acc0, 0, 0, 0);
      acc1 = __builtin_amdgcn_mfma_f32_16x16x32_bf16(bh1, alo, acc1, 0, 0, 0);
      acc0 = __builtin_amdgcn_mfma_f32_16x16x32_bf16(bl0, ahi, acc0, 0, 0, 0);
      acc1 = __builtin_amdgcn_mfma_f32_16x16x32_bf16(bl1, ahi, acc1, 0, 0, 0);
    }
    if ((q & 7) == 7) {
      // lane's column m is fixed per tile; magic-div once, then 8 coalesced stores
      const unsigned m = (unsigned)(row0 + (size_t)(q >> 3) * 128 + wave * 16 + (lane & 15));
      const unsigned tb = (unsigned)(((unsigned long long)m * 1374389535ull) >> 36);
      const unsigned l = m - tb * 50u;
      float* basep = dp + (size_t)tb * 1792 + l;
#pragma unroll
      for (int reg = 0; reg < 4; ++reg) {
        basep[(h0 + reg) * 52] = acc0[reg];
        basep[(16 + h0 + reg) * 52] = acc1[reg];
      }
    }
  }
#undef STAGE
}

// ---------------------------------------------------------------------------
// seq4 (unchanged from rounds 9-11)
// ---------------------------------------------------------------------------
__global__ __launch_bounds__(64, 1) void seq4(
    const float* __restrict__ h0, const float* __restrict__ c0,
    const float* __restrict__ W_attn,
    const float* __restrict__ W_ih, const float* __restrict__ b_ih,
    const float* __restrict__ W_hh, const float* __restrict__ b_hh,
    const float* __restrict__ W_mid, const float* __restrict__ b_mid,
    const float* __restrict__ W_out, const float* __restrict__ b_out,
    const float* __restrict__ ws, float* __restrict__ out) {
  __shared__ alignas(16) float dpb[4][1792];
  __shared__ alignas(16) float lcb[4][64];
  __shared__ alignas(16) float ccb[4][64];
  __shared__ alignas(16) float sw[56];
  __shared__ alignas(16) float hist[T_ * 33];
  __shared__ float swq[576];
  __shared__ float sbq[20];
  const int b = blockIdx.x, lane = threadIdx.x, hh = lane & 31;
  const float* lcg = ws + WS_LC;
  const float* ccg = ws + WS_CC;
  const float* dpg = ws + WS_DP;

  float wA2[32], wia[32], wib[32], wha[32], whb[32];
  const int l_eff = lane < 50 ? lane : 49;
#pragma unroll
  for (int k = 0; k < 32; ++k) {
    wA2[k] = W_attn[(size_t)l_eff * 544 + 512 + k];
    wia[k] = W_ih[lane * 32 + k];
    wib[k] = W_ih[(64 + lane) * 32 + k];
    wha[k] = W_hh[lane * 32 + k];
    whb[k] = W_hh[(64 + lane) * 32 + k];
  }
  const float bga = b_ih[lane] + b_hh[lane];
  const float bgb = b_ih[64 + lane] + b_hh[64 + lane];
  float h = h0[b * 32 + hh], c = c0[b * 32 + hh];

#pragma unroll
  for (int tt = 0; tt < 3; ++tt) {
    const size_t rown = (size_t)tt * B_ + b;
    const float* dsrc = dpg + rown * 1792;
#pragma unroll
    for (int i = 0; i < 7; ++i) glds16(dsrc + i * 256 + lane * 4, &dpb[tt][i * 256]);
    glds4(lcg + rown * 50 + lane, &lcb[tt][0]);
    glds4(ccg + rown * 32 + lane, &ccb[tt][0]);
  }

  for (int idx = lane; idx < 576; idx += 64) {
    int a = idx >> 5, k = idx & 31;
    float acc = 0.f;
#pragma unroll
    for (int m = 0; m < 64; ++m) acc = fmaf(W_out[a * 64 + m], W_mid[m * 32 + k], acc);
    swq[k * 18 + a] = acc;
  }
  if (lane < 18) {
    float acc = b_out[lane];
#pragma unroll
    for (int m = 0; m < 64; ++m) acc = fmaf(W_out[lane * 64 + m], b_mid[m], acc);
    sbq[lane] = acc;
  }

  for (int t = 0; t < T_; ++t) {
    const int p = t & 3, pn = (t + 3) & 3;
    {
      const size_t rown = (size_t)(t + 3) * B_ + b;
      const float* dsrc = dpg + rown * 1792;
#pragma unroll
      for (int i = 0; i < 7; ++i) glds16(dsrc + i * 256 + lane * 4, &dpb[pn][i * 256]);
      glds4(lcg + rown * 50 + lane, &lcb[pn][0]);
      glds4(ccg + rown * 32 + lane, &ccb[pn][0]);
    }
    asm volatile("s_waitcnt vmcnt(27)" ::: "memory");
    __builtin_amdgcn_sched_barrier(0);

    float lg0 = 0.f, lg1 = 0.f;
#pragma unroll
    for (int k = 0; k < 32; k += 2) {
      lg0 = fmaf(bcast(h, k), wA2[k], lg0);
      lg1 = fmaf(bcast(h, k + 1), wA2[k + 1], lg1);
    }
    const float logit = (lane < 50) ? (lcb[p][lane] + lg0 + lg1) : -1e30f;
    float mx = logit;
#pragma unroll
    for (int off = 32; off; off >>= 1) mx = fmaxf(mx, __shfl_xor(mx, off, 64));
    const float e = (lane < 50) ? expf(logit - mx) : 0.f;
    float se = e;
#pragma unroll
    for (int off = 32; off; off >>= 1) se += __shfl_xor(se, off, 64);
    const float wsm = e / se;

    if (lane < 56) sw[lane] = wsm;
    const f32x4* sw4 = (const f32x4*)sw;
    const f32x4* dp4 = (const f32x4*)&dpb[p][hh * 52];
    f32x4 av = {0.f, 0.f, 0.f, 0.f};
    if (lane < 32) {
#pragma unroll
      for (int j = 0; j < 6; ++j) av += sw4[j] * dp4[j];
    } else {
#pragma unroll
      for (int j = 6; j < 13; ++j) av += sw4[j] * dp4[j];
    }
    float part = (av[0] + av[1]) + (av[2] + av[3]);
    part += __shfl_xor(part, 32, 64);
    const float x = fmaxf(part + ccb[p][hh], 0.f);

    float ga0 = bga, ga1 = 0.f, gb0 = bgb, gb1 = 0.f;
#pragma unroll
    for (int k = 0; k < 32; k += 2) {
      float xv0 = bcast(x, k), hv0 = bcast(h, k);
      float xv1 = bcast(x, k + 1), hv1 = bcast(h, k + 1);
      ga0 = fmaf(xv0, wia[k], ga0);     ga0 = fmaf(hv0, wha[k], ga0);
      ga1 = fmaf(xv1, wia[k + 1], ga1); ga1 = fmaf(hv1, wha[k + 1], ga1);
      gb0 = fmaf(xv0, wib[k], gb0);     gb0 = fmaf(hv0, whb[k], gb0);
      gb1 = fmaf(xv1, wib[k + 1], gb1); gb1 = fmaf(hv1, whb[k + 1], gb1);
    }
    const float ga = ga0 + ga1, gb = gb0 + gb1;
    const float xga = __shfl_xor(ga, 32, 64), xgb = __shfl_xor(gb, 32, 64);
    const bool low = lane < 32;
    const float iv = low ? ga : xga, fv = low ? xga : ga;
    const float gv = low ? gb : xgb, ov = low ? xgb : gb;
    c = sigf(fv) * c + sigf(iv) * tanhf(gv);
    h = sigf(ov) * tanhf(c);
    if (lane < 32) hist[t * 33 + hh] = h;
  }

  for (int idx = lane; idx < T_ * A_; idx += 64) {
    int t = idx / A_, a = idx - t * A_;
    float acc = sbq[a];
#pragma unroll
    for (int k = 0; k < 32; ++k) acc = fmaf(hist[t * 33 + k], swq[k * 18 + a], acc);
    out[((size_t)t * B_ + b) * A_ + a] = acc;
  }
  if (lane < 32) {
    out[(size_t)T_ * B_ * A_ + (size_t)b * H_ + lane] = h;
    out[(size_t)T_ * B_ * A_ + (size_t)B_ * H_ + (size_t)b * H_ + lane] = c;
  }
}

extern "C" void kernel_launch(void* const* d_in, const int* in_sizes, int n_in,
                              void* d_out, int out_size, void* d_ws, size_t ws_size,
                              hipStream_t stream) {
  const float* state  = (const float*)d_in[0];
  const float* demo   = (const float*)d_in[1];
  const float* h0     = (const float*)d_in[2];
  const float* c0     = (const float*)d_in[3];
  const float* W_attn = (const float*)d_in[4];
  const float* b_attn = (const float*)d_in[5];
  const float* W_comb = (const float*)d_in[6];
  const float* b_comb = (const float*)d_in[7];
  const float* W_ih   = (const float*)d_in[8];
  const float* b_ih   = (const float*)d_in[9];
  const float* W_hh   = (const float*)d_in[10];
  const float* b_hh   = (const float*)d_in[11];
  const float* W_mid  = (const float*)d_in[12];
  const float* b_mid  = (const float*)d_in[13];
  const float* W_out  = (const float*)d_in[14];
  const float* b_out  = (const float*)d_in[15];
  float* out = (float*)d_out;
  float* ws  = (float*)d_ws;

  constexpr int pm4_smem = 81920;
  (void)hipFuncSetAttribute(reinterpret_cast<const void*>(precompute4),
                            hipFuncAttributeMaxDynamicSharedMemorySize, pm4_smem);
  precompute4<<<dim3(256), dim3(256), pm4_smem, stream>>>(
      state, W_attn, b_attn, W_comb, b_comb, ws + WS_LC, ws + WS_CC);

  constexpr int dp5_smem = 163840;   // 96 KB A-ring + 64 KB B-frags
  (void)hipFuncSetAttribute(reinterpret_cast<const void*>(dp_gemm5),
                            hipFuncAttributeMaxDynamicSharedMemorySize, dp5_smem);
  dp_gemm5<<<dim3(256), dim3(512), dp5_smem, stream>>>(demo, W_comb, ws + WS_DP);

  seq4<<<dim3(256), dim3(64), 0, stream>>>(
      h0, c0, W_attn, W_ih, b_ih, W_hh, b_hh,
      W_mid, b_mid, W_out, b_out, ws, out);
}

// Round 13
// 550.856 us; speedup vs baseline: 1.0625x; 1.0625x over previous
//
#include <hip/hip_runtime.h>
#include <cstddef>

#define T_ 64
#define B_ 256
#define D_ 512
#define L_ 50
#define A_ 18
#define H_ 32

typedef __attribute__((ext_vector_type(8))) short short8;
typedef __attribute__((ext_vector_type(4))) float f32x4;

// ---- workspace float offsets ----
constexpr size_t WS_LC = 0;              // [16384*50]
constexpr size_t WS_CC = 819200;         // [16384*32]
constexpr size_t WS_DP = 1868416;        // [819200][32]  dp[m][h], m=(t*B+b)*50+l

__device__ __forceinline__ float sigf(float x) { return 1.f / (1.f + expf(-x)); }

__device__ __forceinline__ short f2bf_rne(float f) {
  unsigned u = __float_as_uint(f);
  return (short)((u + 0x7fffu + ((u >> 16) & 1u)) >> 16);
}
__device__ __forceinline__ float bcast(float v, int l) {
  return __int_as_float(__builtin_amdgcn_readlane(__float_as_int(v), l));
}
__device__ __forceinline__ void glds16(const float* g, float* l) {
  __builtin_amdgcn_global_load_lds((const __attribute__((address_space(1))) unsigned*)g,
                                   (__attribute__((address_space(3))) unsigned*)l, 16, 0, 0);
}
__device__ __forceinline__ void glds4(const float* g, float* l) {
  __builtin_amdgcn_global_load_lds((const __attribute__((address_space(1))) unsigned*)g,
                                   (__attribute__((address_space(3))) unsigned*)l, 4, 0, 0);
}

// ---------------------------------------------------------------------------
// precompute4 (unchanged, proven rounds 9-12)
// ---------------------------------------------------------------------------
__global__ __launch_bounds__(256) void precompute4(
    const float* __restrict__ state,
    const float* __restrict__ W_attn, const float* __restrict__ b_attn,
    const float* __restrict__ W_comb, const float* __restrict__ b_comb,
    float* __restrict__ lc, float* __restrict__ cc) {
  extern __shared__ char pm3[];
  float* As = (float*)pm3;                 // [4 slots][4 waves][512] = 32 KB
  short* Bf = (short*)(pm3 + 32768);       // [2 hi/lo][4 kc][6 nt][64][8] = 48 KB
  const int tid = threadIdx.x;
  const int wave = tid >> 6, lane = tid & 63;
  const int r0 = blockIdx.x * 64;

  const int srow = lane >> 3;
  const int scol = (((lane & 7) * 16) ^ (srow << 4)) >> 2;
  const int crow = lane & 15, g = lane >> 4;
  const int cb0 = (g * 32) ^ ((crow & 7) << 4);

  f32x4 acc[6];
#pragma unroll
  for (int nt = 0; nt < 6; ++nt) acc[nt] = {0.f, 0.f, 0.f, 0.f};

#define STAGE_A(KI, SLOT)                                                       \
  {                                                                             \
    float* dst_ = As + ((SLOT) * 4 + wave) * 512;                               \
    _Pragma("unroll")                                                           \
    for (int i_ = 0; i_ < 2; ++i_) {                                            \
      const float* src_ = state +                                               \
          (size_t)(r0 + wave * 16 + i_ * 8 + srow) * 512 + (KI) * 32 + scol;    \
      glds16(src_, dst_ + i_ * 256);                                            \
    }                                                                           \
  }

  auto stageB = [&](int ko) {
#pragma unroll
    for (int it = 0; it < 6; ++it) {
      int u = tid + it * 256;
      int l = u & 63;
      int nt = (u >> 6) % 6;
      int c = u / 384;
      int n = nt * 16 + (l & 15);
      int kb = ko * 128 + c * 32 + ((l >> 4) << 3);
      f32x4 v0 = {0.f, 0.f, 0.f, 0.f}, v1 = {0.f, 0.f, 0.f, 0.f};
      if (n < 50) {
        const f32x4* s = (const f32x4*)(W_attn + (size_t)n * 544 + kb);
        v0 = s[0]; v1 = s[1];
      } else if (n < 82) {
        const f32x4* s = (const f32x4*)(W_comb + (size_t)(n - 50) * 1024 + 512 + kb);
        v0 = s[0]; v1 = s[1];
      }
      short8 hi, lo;
#pragma unroll
      for (int j = 0; j < 4; ++j) {
        unsigned ua = __float_as_uint(v0[j]), ha = ua & 0xffff0000u;
        hi[j] = (short)(ha >> 16);
        lo[j] = f2bf_rne(v0[j] - __uint_as_float(ha));
        unsigned ub = __float_as_uint(v1[j]), hb = ub & 0xffff0000u;
        hi[4 + j] = (short)(hb >> 16);
        lo[4 + j] = f2bf_rne(v1[j] - __uint_as_float(hb));
      }
      *(short8*)&Bf[(((0 * 4 + c) * 6 + nt) * 64 + l) * 8] = hi;
      *(short8*)&Bf[(((1 * 4 + c) * 6 + nt) * 64 + l) * 8] = lo;
    }
  };

  STAGE_A(0, 0);
  STAGE_A(1, 1);
  STAGE_A(2, 2);
  stageB(0);
  asm volatile("s_waitcnt lgkmcnt(0)" ::: "memory");
  __builtin_amdgcn_s_barrier();

  for (int ko = 0; ko < 4; ++ko) {
    if (ko > 0) {
      __builtin_amdgcn_s_barrier();
      stageB(ko);
      asm volatile("s_waitcnt lgkmcnt(0)" ::: "memory");
      __builtin_amdgcn_s_barrier();
    }
#pragma unroll
    for (int c = 0; c < 4; ++c) {
      const int ki = ko * 4 + c;
      if (ki < 13) {
        STAGE_A(ki + 3, (ki + 3) & 3);
        asm volatile("s_waitcnt vmcnt(6)" ::: "memory");
      } else if (ki == 13) {
        asm volatile("s_waitcnt vmcnt(4)" ::: "memory");
      } else if (ki == 14) {
        asm volatile("s_waitcnt vmcnt(2)" ::: "memory");
      } else {
        asm volatile("s_waitcnt vmcnt(0)" ::: "memory");
      }
      __builtin_amdgcn_sched_barrier(0);
      const char* ab = (const char*)(As + ((ki & 3) * 4 + wave) * 512) + crow * 128;
      f32x4 a0 = *(const f32x4*)(ab + cb0);
      f32x4 a1 = *(const f32x4*)(ab + (cb0 ^ 16));
      short8 ahi, alo;
#pragma unroll
      for (int j = 0; j < 4; ++j) {
        unsigned ua = __float_as_uint(a0[j]), ha = ua & 0xffff0000u;
        ahi[j] = (short)(ha >> 16);
        alo[j] = f2bf_rne(a0[j] - __uint_as_float(ha));
        unsigned ub = __float_as_uint(a1[j]), hb = ub & 0xffff0000u;
        ahi[4 + j] = (short)(hb >> 16);
        alo[4 + j] = f2bf_rne(a1[j] - __uint_as_float(hb));
      }
#pragma unroll
      for (int nt = 0; nt < 6; ++nt) {
        short8 bh = *(const short8*)&Bf[(((0 * 4 + c) * 6 + nt) * 64 + lane) * 8];
        short8 bl = *(const short8*)&Bf[(((1 * 4 + c) * 6 + nt) * 64 + lane) * 8];
        acc[nt] = __builtin_amdgcn_mfma_f32_16x16x32_bf16(ahi, bh, acc[nt], 0, 0, 0);
        acc[nt] = __builtin_amdgcn_mfma_f32_16x16x32_bf16(alo, bh, acc[nt], 0, 0, 0);
        acc[nt] = __builtin_amdgcn_mfma_f32_16x16x32_bf16(ahi, bl, acc[nt], 0, 0, 0);
      }
    }
  }
#undef STAGE_A

#pragma unroll
  for (int nt = 0; nt < 6; ++nt) {
    const int n = nt * 16 + crow;
    float bias = 0.f;
    if (n < 50) bias = b_attn[n];
    else if (n < 82) bias = b_comb[n - 50];
#pragma unroll
    for (int reg = 0; reg < 4; ++reg) {
      const int r = r0 + wave * 16 + (g << 2) + reg;
      const float vv = acc[nt][reg] + bias;
      if (n < 50) lc[(size_t)r * 50 + n] = vv;
      else if (n < 82) cc[(size_t)r * 32 + (n - 50)] = vv;
    }
  }
}

// ---------------------------------------------------------------------------
// dp_gemm: BITWISE restore of round 5's 375 µs kernel ([m][32] coalesced
// stores, 3-slot A ring, vmcnt(8)/store-aware vmcnt(16)).
// ---------------------------------------------------------------------------
__global__ __launch_bounds__(512, 2) void dp_gemm(const float* __restrict__ demo,
                                                  const float* __restrict__ W_comb,
                                                  float* __restrict__ dp) {
  extern __shared__ char smraw[];
  float* Abuf = (float*)smraw;                    // [3][8192] floats = 96 KB
  short* frag = (short*)(smraw + 98304);          // [2][16][2][64][8] = 64 KB
  const int tid = threadIdx.x;

  for (int f = tid; f < 16384; f += 512) {
    int j = f & 7, l = (f >> 3) & 63, nt = (f >> 9) & 1, c = f >> 10;
    int n = nt * 16 + (l & 15);
    int k = c * 32 + ((l >> 4) << 3) + j;
    float v = W_comb[(size_t)n * 1024 + k];
    unsigned u = __float_as_uint(v);
    unsigned hb = u & 0xffff0000u;
    frag[(((0 * 16 + c) * 2 + nt) * 64 + l) * 8 + j] = (short)(hb >> 16);
    frag[(((1 * 16 + c) * 2 + nt) * 64 + l) * 8 + j] = f2bf_rne(v - __uint_as_float(hb));
  }
  __syncthreads();

  const int wave = tid >> 6, lane = tid & 63;
  const size_t row0 = (size_t)blockIdx.x * 3200;

  int rrl[4], gcol[4];
#pragma unroll
  for (int i = 0; i < 4; ++i) {
    rrl[i] = wave * 16 + i * 4 + (lane >> 4);
    gcol[i] = ((((lane & 15) * 16) ^ ((rrl[i] & 7) << 4)) >> 2);
  }
  const int rr = wave * 16 + (lane & 15);
  const int g = lane >> 4;

  f32x4 acc0 = {0.f, 0.f, 0.f, 0.f}, acc1 = {0.f, 0.f, 0.f, 0.f};

#define STAGE(Q, SLOT)                                                          \
  {                                                                             \
    const int tile_ = (Q) >> 3, kc_ = (Q) & 7;                                  \
    const size_t rbase_ = row0 + (size_t)tile_ * 128;                           \
    float* dst_ = Abuf + (SLOT) * 8192 + wave * 1024;                           \
    _Pragma("unroll")                                                           \
    for (int i = 0; i < 4; ++i) {                                               \
      const float* src_ = demo + (rbase_ + rrl[i]) * 512 + kc_ * 64 + gcol[i];  \
      glds16(src_, dst_ + i * 256);                                             \
    }                                                                           \
  }

  STAGE(0, 0);
  STAGE(1, 1);
  for (int q = 0; q < 200; ++q) {
    const int q2 = (q + 2 < 200) ? q + 2 : 199;
    STAGE(q2, (q + 2) % 3);
    if (q >= 8 && (q & 7) <= 1) {
      asm volatile("s_waitcnt vmcnt(16)" ::: "memory");
    } else {
      asm volatile("s_waitcnt vmcnt(8)" ::: "memory");
    }
    __builtin_amdgcn_sched_barrier(0);
    if ((q & 7) == 0) {
      acc0 = {0.f, 0.f, 0.f, 0.f};
      acc1 = {0.f, 0.f, 0.f, 0.f};
    }
    const char* ab = (const char*)(Abuf + (q % 3) * 8192) + rr * 256;
#pragma unroll
    for (int sub = 0; sub < 2; ++sub) {
      const int b0 = (sub * 128 + g * 32) ^ ((rr & 7) << 4);
      f32x4 a0 = *(const f32x4*)(ab + b0);
      f32x4 a1 = *(const f32x4*)(ab + (b0 ^ 16));
      short8 ahi, alo;
#pragma unroll
      for (int j = 0; j < 4; ++j) {
        float v = a0[j];
        unsigned u = __float_as_uint(v), hb = u & 0xffff0000u;
        ahi[j] = (short)(hb >> 16);
        alo[j] = f2bf_rne(v - __uint_as_float(hb));
        float w = a1[j];
        unsigned u2 = __float_as_uint(w), hb2 = u2 & 0xffff0000u;
        ahi[4 + j] = (short)(hb2 >> 16);
        alo[4 + j] = f2bf_rne(w - __uint_as_float(hb2));
      }
      const int ck = (q & 7) * 2 + sub;
      short8 bh0 = *(const short8*)&frag[(((0 + ck) * 2 + 0) * 64 + lane) * 8];
      short8 bh1 = *(const short8*)&frag[(((0 + ck) * 2 + 1) * 64 + lane) * 8];
      short8 bl0 = *(const short8*)&frag[(((16 + ck) * 2 + 0) * 64 + lane) * 8];
      short8 bl1 = *(const short8*)&frag[(((16 + ck) * 2 + 1) * 64 + lane) * 8];
      acc0 = __builtin_amdgcn_mfma_f32_16x16x32_bf16(ahi, bh0, acc0, 0, 0, 0);
      acc1 = __builtin_amdgcn_mfma_f32_16x16x32_bf16(ahi, bh1, acc1, 0, 0, 0);
      acc0 = __builtin_amdgcn_mfma_f32_16x16x32_bf16(alo, bh0, acc0, 0, 0, 0);
      acc1 = __builtin_amdgcn_mfma_f32_16x16x32_bf16(alo, bh1, acc1, 0, 0, 0);
      acc0 = __builtin_amdgcn_mfma_f32_16x16x32_bf16(ahi, bl0, acc0, 0, 0, 0);
      acc1 = __builtin_amdgcn_mfma_f32_16x16x32_bf16(ahi, bl1, acc1, 0, 0, 0);
    }
    if ((q & 7) == 7) {
      float* drow = dp + (row0 + (size_t)(q >> 3) * 128 + wave * 16) * 32;
#pragma unroll
      for (int reg = 0; reg < 4; ++reg) {
        int r = ((lane >> 4) << 2) + reg;
        drow[r * 32 + (lane & 15)] = acc0[reg];
        drow[r * 32 + 16 + (lane & 15)] = acc1[reg];
      }
    }
  }
#undef STAGE
}

// ---------------------------------------------------------------------------
// seq5: 1 wave per batch element. dp in ORIGINAL [50][32] layout; x-phase
// vectorized over h: lane=(ls=lane>>3, hg=lane&7), f32x4 accumulation +
// shfl_xor(8,16,32) reduce. Depth-3 prefetch (vmcnt(27)); wq-fold + q fused.
// ---------------------------------------------------------------------------
__global__ __launch_bounds__(64, 1) void seq5(
    const float* __restrict__ h0, const float* __restrict__ c0,
    const float* __restrict__ W_attn,
    const float* __restrict__ W_ih, const float* __restrict__ b_ih,
    const float* __restrict__ W_hh, const float* __restrict__ b_hh,
    const float* __restrict__ W_mid, const float* __restrict__ b_mid,
    const float* __restrict__ W_out, const float* __restrict__ b_out,
    const float* __restrict__ ws, float* __restrict__ out) {
  __shared__ alignas(16) float dpb[4][1792];   // [50][32] + zero tail to l=56
  __shared__ alignas(16) float lcb[4][64];
  __shared__ alignas(16) float ccb[4][64];
  __shared__ alignas(16) float sw[56];
  __shared__ alignas(16) float hist[T_ * 33];
  __shared__ float swq[576];
  __shared__ float sbq[20];
  const int b = blockIdx.x, lane = threadIdx.x, hh = lane & 31;
  const int ls = lane >> 3, hg = lane & 7;
  const float* lcg = ws + WS_LC;
  const float* ccg = ws + WS_CC;
  const float* dpg = ws + WS_DP;

  float wA2[32], wia[32], wib[32], wha[32], whb[32];
  const int l_eff = lane < 50 ? lane : 49;
#pragma unroll
  for (int k = 0; k < 32; ++k) {
    wA2[k] = W_attn[(size_t)l_eff * 544 + 512 + k];
    wia[k] = W_ih[lane * 32 + k];
    wib[k] = W_ih[(64 + lane) * 32 + k];
    wha[k] = W_hh[lane * 32 + k];
    whb[k] = W_hh[(64 + lane) * 32 + k];
  }
  const float bga = b_ih[lane] + b_hh[lane];
  const float bgb = b_ih[64 + lane] + b_hh[64 + lane];
  float h = h0[b * 32 + hh], c = c0[b * 32 + hh];

  // zero the l=50..55 tails (read as 0-weighted garbage guards)
#pragma unroll
  for (int s = 0; s < 4; ++s) {
    for (int idx = lane; idx < 192; idx += 64) dpb[s][1600 + idx] = 0.f;
  }
  asm volatile("s_waitcnt lgkmcnt(0)" ::: "memory");

#pragma unroll
  for (int tt = 0; tt < 3; ++tt) {   // prefetch t=0,1,2 (9 loads each)
    const size_t rown = (size_t)tt * B_ + b;
    const float* dsrc = dpg + rown * 1600;
#pragma unroll
    for (int i = 0; i < 6; ++i) glds16(dsrc + i * 256 + lane * 4, &dpb[tt][i * 256]);
    glds4(dsrc + 1536 + lane, &dpb[tt][1536]);
    glds4(lcg + rown * 50 + lane, &lcb[tt][0]);
    glds4(ccg + rown * 32 + lane, &ccb[tt][0]);
  }

  // fold Wq = W_out@W_mid + bq while prefetch is in flight
  for (int idx = lane; idx < 576; idx += 64) {
    int a = idx >> 5, k = idx & 31;
    float acc = 0.f;
#pragma unroll
    for (int m = 0; m < 64; ++m) acc = fmaf(W_out[a * 64 + m], W_mid[m * 32 + k], acc);
    swq[k * 18 + a] = acc;
  }
  if (lane < 18) {
    float acc = b_out[lane];
#pragma unroll
    for (int m = 0; m < 64; ++m) acc = fmaf(W_out[lane * 64 + m], b_mid[m], acc);
    sbq[lane] = acc;
  }

  for (int t = 0; t < T_; ++t) {
    const int p = t & 3, pn = (t + 3) & 3;
    {
      const size_t rown = (size_t)(t + 3) * B_ + b;  // overreads stay inside ws
      const float* dsrc = dpg + rown * 1600;
#pragma unroll
      for (int i = 0; i < 6; ++i) glds16(dsrc + i * 256 + lane * 4, &dpb[pn][i * 256]);
      glds4(dsrc + 1536 + lane, &dpb[pn][1536]);
      glds4(lcg + rown * 50 + lane, &lcb[pn][0]);
      glds4(ccg + rown * 32 + lane, &ccb[pn][0]);
    }
    asm volatile("s_waitcnt vmcnt(27)" ::: "memory");
    __builtin_amdgcn_sched_barrier(0);

    // logits (lane l<50): lc + h·W_attn[l,512:]
    float lg0 = 0.f, lg1 = 0.f;
#pragma unroll
    for (int k = 0; k < 32; k += 2) {
      lg0 = fmaf(bcast(h, k), wA2[k], lg0);
      lg1 = fmaf(bcast(h, k + 1), wA2[k + 1], lg1);
    }
    const float logit = (lane < 50) ? (lcb[p][lane] + lg0 + lg1) : -1e30f;
    float mx = logit;
#pragma unroll
    for (int off = 32; off; off >>= 1) mx = fmaxf(mx, __shfl_xor(mx, off, 64));
    const float e = (lane < 50) ? expf(logit - mx) : 0.f;
    float se = e;
#pragma unroll
    for (int off = 32; off; off >>= 1) se += __shfl_xor(se, off, 64);
    const float wsm = e / se;    // == 0 for lanes >= 50

    // x[h] = relu( sum_l w[l]·dp[l][h] + cc[h] ), vectorized over h:
    // lane (ls, hg) accumulates f32x4 over l = ls + 8j, then reduce over ls.
    if (lane < 56) sw[lane] = wsm;
    const f32x4* dp4 = (const f32x4*)dpb[p];
    f32x4 av = {0.f, 0.f, 0.f, 0.f};
#pragma unroll
    for (int j = 0; j < 7; ++j) {
      const int l = ls + j * 8;        // <= 55; sw[l]=0 for l>=50, tail zeroed
      const float wl = sw[l];
      const f32x4 d = dp4[l * 8 + hg];
      av += wl * d;
    }
#pragma unroll
    for (int off = 8; off < 64; off <<= 1) {
      av[0] += __shfl_xor(av[0], off, 64);
      av[1] += __shfl_xor(av[1], off, 64);
      av[2] += __shfl_xor(av[2], off, 64);
      av[3] += __shfl_xor(av[3], off, 64);
    }
    const f32x4 cc4 = *(const f32x4*)&ccb[p][hg * 4];
    f32x4 xv4;
#pragma unroll
    for (int j = 0; j < 4; ++j) xv4[j] = fmaxf(av[j] + cc4[j], 0.f);

    // gates: lane owns rows lane (i|f) and 64+lane (g|o); x[k] via readlane
    float ga0 = bga, ga1 = 0.f, gb0 = bgb, gb1 = 0.f;
#pragma unroll
    for (int k = 0; k < 32; k += 2) {
      float xv0 = bcast(xv4[k & 3], k >> 2), hv0 = bcast(h, k);
      float xv1 = bcast(xv4[(k + 1) & 3], (k + 1) >> 2), hv1 = bcast(h, k + 1);
      ga0 = fmaf(xv0, wia[k], ga0);     ga0 = fmaf(hv0, wha[k], ga0);
      ga1 = fmaf(xv1, wia[k + 1], ga1); ga1 = fmaf(hv1, wha[k + 1], ga1);
      gb0 = fmaf(xv0, wib[k], gb0);     gb0 = fmaf(hv0, whb[k], gb0);
      gb1 = fmaf(xv1, wib[k + 1], gb1); gb1 = fmaf(hv1, whb[k + 1], gb1);
    }
    const float ga = ga0 + ga1, gb = gb0 + gb1;
    const float xga = __shfl_xor(ga, 32, 64), xgb = __shfl_xor(gb, 32, 64);
    const bool low = lane < 32;
    const float iv = low ? ga : xga, fv = low ? xga : ga;
    const float gv = low ? gb : xgb, ov = low ? xgb : gb;
    c = sigf(fv) * c + sigf(iv) * tanhf(gv);
    h = sigf(ov) * tanhf(c);
    if (lane < 32) hist[t * 33 + hh] = h;
  }

  // q[t,a] = hist[t,:]·Wq[:,a] + bq[a]
  for (int idx = lane; idx < T_ * A_; idx += 64) {
    int t = idx / A_, a = idx - t * A_;
    float acc = sbq[a];
#pragma unroll
    for (int k = 0; k < 32; ++k) acc = fmaf(hist[t * 33 + k], swq[k * 18 + a], acc);
    out[((size_t)t * B_ + b) * A_ + a] = acc;
  }
  if (lane < 32) {
    out[(size_t)T_ * B_ * A_ + (size_t)b * H_ + lane] = h;
    out[(size_t)T_ * B_ * A_ + (size_t)B_ * H_ + (size_t)b * H_ + lane] = c;
  }
}

extern "C" void kernel_launch(void* const* d_in, const int* in_sizes, int n_in,
                              void* d_out, int out_size, void* d_ws, size_t ws_size,
                              hipStream_t stream) {
  const float* state  = (const float*)d_in[0];
  const float* demo   = (const float*)d_in[1];
  const float* h0     = (const float*)d_in[2];
  const float* c0     = (const float*)d_in[3];
  const float* W_attn = (const float*)d_in[4];
  const float* b_attn = (const float*)d_in[5];
  const float* W_comb = (const float*)d_in[6];
  const float* b_comb = (const float*)d_in[7];
  const float* W_ih   = (const float*)d_in[8];
  const float* b_ih   = (const float*)d_in[9];
  const float* W_hh   = (const float*)d_in[10];
  const float* b_hh   = (const float*)d_in[11];
  const float* W_mid  = (const float*)d_in[12];
  const float* b_mid  = (const float*)d_in[13];
  const float* W_out  = (const float*)d_in[14];
  const float* b_out  = (const float*)d_in[15];
  float* out = (float*)d_out;
  float* ws  = (float*)d_ws;

  constexpr int pm4_smem = 81920;
  (void)hipFuncSetAttribute(reinterpret_cast<const void*>(precompute4),
                            hipFuncAttributeMaxDynamicSharedMemorySize, pm4_smem);
  precompute4<<<dim3(256), dim3(256), pm4_smem, stream>>>(
      state, W_attn, b_attn, W_comb, b_comb, ws + WS_LC, ws + WS_CC);

  constexpr int dp_smem = 163840;   // 96 KB A-ring + 64 KB B-frags
  (void)hipFuncSetAttribute(reinterpret_cast<const void*>(dp_gemm),
                            hipFuncAttributeMaxDynamicSharedMemorySize, dp_smem);
  dp_gemm<<<dim3(256), dim3(512), dp_smem, stream>>>(demo, W_comb, ws + WS_DP);

  seq5<<<dim3(256), dim3(64), 0, stream>>>(
      h0, c0, W_attn, W_ih, b_ih, W_hh, b_hh,
      W_mid, b_mid, W_out, b_out, ws, out);
}